// Round 1
// baseline (911.353 us; speedup 1.0000x reference)
//
#include <hip/hip_runtime.h>
#include <stdint.h>

// Group / KNN kernel for:
//   B=16, N=16384, NUM_GROUP=512, GROUP_SIZE=32
// Outputs (concatenated flat in d_out, all read back as float32):
//   neighborhood [16][512][32][3]  (786432 floats)  = xyz[idx] - center
//   center       [16][512][3]      (24576 floats)
//   ids          [16][512]         (8192 floats)    = g*32
//
// Ordering contract: jax.lax.top_k(-sqr, 32) == 32 smallest sqr, ascending,
// ties broken by smaller point index. We select on a packed 64-bit key
// (monotonic-transformed float bits << 32) | point_index, which reproduces
// that ordering exactly given bit-identical sqr values.
//
// sqr is computed with NO fma and left-to-right association to mimic the
// reference elementwise lowering:
//   dot = ((c0*x0 + c1*x1) + c2*x2)
//   cs  = ((c0*c0 + c1*c1) + c2*c2),  xs likewise
//   sqr = ((-2*dot) + cs) + xs

#define TB   256   // threads per block (one block per (b,g) group)
#define PPT  64    // points per thread = 16384 / 256

__global__ __launch_bounds__(TB) void group_knn_kernel(
    const float* __restrict__ xyz,   // [16][16384][3]
    float* __restrict__ out_nb,      // [16][512][32][3]
    float* __restrict__ out_ctr,     // [16][512][3]
    float* __restrict__ out_ids)     // [16][512] (float-valued ints)
{
    const int NPTS = 16384;
    const int NGRP = 512;
    const int GSZ  = 32;

    const int bg = blockIdx.x;           // 0 .. 8191
    const int b  = bg >> 9;              // / 512
    const int g  = bg & (NGRP - 1);
    const int t  = threadIdx.x;
    const int nc = g * 32;               // center point index (sel[g])

    const float* base = xyz + (size_t)b * NPTS * 3;
    const float c0 = base[nc * 3 + 0];
    const float c1 = base[nc * 3 + 1];
    const float c2 = base[nc * 3 + 2];
    const float cs = __fadd_rn(__fadd_rn(__fmul_rn(c0, c0), __fmul_rn(c1, c1)),
                               __fmul_rn(c2, c2));

    // Phase 1: each thread computes sqr for points n = i*256 + t,
    // stores the order-transformed float bits in registers.
    unsigned ord[PPT];
#pragma unroll
    for (int i = 0; i < PPT; ++i) {
        const int n = i * TB + t;
        const float x0 = base[n * 3 + 0];
        const float x1 = base[n * 3 + 1];
        const float x2 = base[n * 3 + 2];
        const float dot = __fadd_rn(__fadd_rn(__fmul_rn(c0, x0), __fmul_rn(c1, x1)),
                                    __fmul_rn(c2, x2));
        const float xs  = __fadd_rn(__fadd_rn(__fmul_rn(x0, x0), __fmul_rn(x1, x1)),
                                    __fmul_rn(x2, x2));
        const float sqr = __fadd_rn(__fadd_rn(__fmul_rn(-2.0f, dot), cs), xs);
        // monotonic transform: handles (rare) tiny negative sqr from cancellation
        unsigned u = __float_as_uint(sqr);
        u = (u & 0x80000000u) ? ~u : (u | 0x80000000u);
        ord[i] = u;
    }

    // running per-thread min key
    unsigned long long mymin = ((unsigned long long)ord[0] << 32) | (unsigned)t;
#pragma unroll
    for (int i = 1; i < PPT; ++i) {
        unsigned long long kk =
            ((unsigned long long)ord[i] << 32) | (unsigned)(i * TB + t);
        mymin = (kk < mymin) ? kk : mymin;
    }

    __shared__ unsigned long long s_part[TB / 64];
    __shared__ unsigned s_win[32];

    // Phase 2: 32 exact argmin extractions
    for (int k = 0; k < GSZ; ++k) {
        unsigned long long v = mymin;
#pragma unroll
        for (int m = 32; m >= 1; m >>= 1) {
            unsigned long long o = __shfl_xor(v, m, 64);
            v = (o < v) ? o : v;
        }
        if ((t & 63) == 0) s_part[t >> 6] = v;
        __syncthreads();
        unsigned long long gk = s_part[0];
#pragma unroll
        for (int w = 1; w < TB / 64; ++w) {
            unsigned long long p = s_part[w];
            gk = (p < gk) ? p : gk;
        }
        if (t == 0) s_win[k] = (unsigned)gk;   // low 32 bits = point index
        if (gk == mymin) {
            // this thread owns the extracted point: remove it, rescan
            const int iwin = ((unsigned)gk) >> 8;   // n / 256
#pragma unroll
            for (int i = 0; i < PPT; ++i)
                if (i == iwin) ord[i] = 0xFFFFFFFFu;
            mymin = ((unsigned long long)ord[0] << 32) | (unsigned)t;
#pragma unroll
            for (int i = 1; i < PPT; ++i) {
                unsigned long long kk =
                    ((unsigned long long)ord[i] << 32) | (unsigned)(i * TB + t);
                mymin = (kk < mymin) ? kk : mymin;
            }
        }
        __syncthreads();
    }

    // Phase 3: outputs
    if (t < GSZ) {
        const unsigned n = s_win[t];
        const float x0 = base[n * 3 + 0];
        const float x1 = base[n * 3 + 1];
        const float x2 = base[n * 3 + 2];
        const size_t ob = (((size_t)bg) * GSZ + t) * 3;
        out_nb[ob + 0] = x0 - c0;
        out_nb[ob + 1] = x1 - c1;
        out_nb[ob + 2] = x2 - c2;
    }
    if (t < 3) out_ctr[(size_t)bg * 3 + t] = base[nc * 3 + t];
    if (t == 0) out_ids[bg] = (float)nc;
}

extern "C" void kernel_launch(void* const* d_in, const int* in_sizes, int n_in,
                              void* d_out, int out_size, void* d_ws, size_t ws_size,
                              hipStream_t stream) {
    const float* xyz = (const float*)d_in[0];
    float* out = (float*)d_out;
    float* out_nb  = out;                        // 786432
    float* out_ctr = out + 786432;               // 24576
    float* out_ids = out + 786432 + 24576;       // 8192
    hipLaunchKernelGGL(group_knn_kernel, dim3(16 * 512), dim3(TB), 0, stream,
                       xyz, out_nb, out_ctr, out_ids);
}

// Round 2
// 167.948 us; speedup vs baseline: 5.4264x; 5.4264x over previous
//
#include <hip/hip_runtime.h>
#include <stdint.h>

// Group / KNN kernel: B=16, N=16384, NUM_GROUP=512, GROUP_SIZE=32.
// Outputs concatenated in d_out (float32):
//   neighborhood [16][512][32][3], center [16][512][3], ids [16][512]
//
// Exact top_k semantics: select on packed 64-bit key
//   (monotonic-transformed sqr bits << 32) | point_index
// -> ascending distance, ties to lower index. sqr computed with non-fma,
// left-to-right association (identical to the round-1 passing kernel).
//
// Algorithm: per-thread min -> per-wave bitonic sort of lane-minima ->
// T = max over waves of 8th-smallest (guarantees >=32 points <= T) ->
// collect candidates <= T into LDS -> counting-sort ranks -> top-32.

#define TB   256   // threads per block (one block per (b,g))
#define PPT  64    // points per thread = 16384 / 256
#define CAP  512   // candidate buffer capacity

__global__ __launch_bounds__(TB) void group_knn_kernel(
    const float* __restrict__ xyz,   // [16][16384][3]
    float* __restrict__ out_nb,      // [16][512][32][3]
    float* __restrict__ out_ctr,     // [16][512][3]
    float* __restrict__ out_ids)     // [16][512]
{
    const int NPTS = 16384;
    const int NGRP = 512;
    const int GSZ  = 32;

    const int bg = blockIdx.x;           // 0 .. 8191
    const int b  = bg >> 9;
    const int g  = bg & (NGRP - 1);
    const int t  = threadIdx.x;
    const int lane = t & 63;
    const int nc = g * 32;               // center point index

    const float* base = xyz + (size_t)b * NPTS * 3;
    const float c0 = base[nc * 3 + 0];
    const float c1 = base[nc * 3 + 1];
    const float c2 = base[nc * 3 + 2];
    const float cs = __fadd_rn(__fadd_rn(__fmul_rn(c0, c0), __fmul_rn(c1, c1)),
                               __fmul_rn(c2, c2));

    __shared__ unsigned long long s_t[4];      // per-wave thresholds / partials
    __shared__ unsigned long long s_cand[CAP];
    __shared__ int s_cnt;
    __shared__ unsigned s_win[32];

    // ---- Phase 1: distances + per-thread packed min --------------------
    unsigned ord[PPT];
    unsigned long long mymin = ~0ull;
#pragma unroll
    for (int i = 0; i < PPT; ++i) {
        const int n = i * TB + t;
        const float x0 = base[n * 3 + 0];
        const float x1 = base[n * 3 + 1];
        const float x2 = base[n * 3 + 2];
        const float dot = __fadd_rn(__fadd_rn(__fmul_rn(c0, x0), __fmul_rn(c1, x1)),
                                    __fmul_rn(c2, x2));
        const float xs  = __fadd_rn(__fadd_rn(__fmul_rn(x0, x0), __fmul_rn(x1, x1)),
                                    __fmul_rn(x2, x2));
        const float sqr = __fadd_rn(__fadd_rn(__fmul_rn(-2.0f, dot), cs), xs);
        unsigned u = __float_as_uint(sqr);
        u = (u & 0x80000000u) ? ~u : (u | 0x80000000u);
        ord[i] = u;
        unsigned long long kk = ((unsigned long long)u << 32) | (unsigned)n;
        mymin = (kk < mymin) ? kk : mymin;
    }

    // ---- Phase 2: wave bitonic sort of lane minima; T_w = 8th smallest --
    {
        unsigned long long v = mymin;
#pragma unroll
        for (int k = 2; k <= 64; k <<= 1) {
#pragma unroll
            for (int j = k >> 1; j > 0; j >>= 1) {
                unsigned long long o = __shfl_xor(v, j, 64);
                const bool up = ((lane & k) == 0);
                const bool takeMin = (((lane & j) == 0) == up);
                unsigned long long mn = (v < o) ? v : o;
                unsigned long long mx = (v < o) ? o : v;
                v = takeMin ? mn : mx;
            }
        }
        if (lane == 7) s_t[t >> 6] = v;   // 8th smallest in this wave
    }
    if (t == 0) s_cnt = 0;
    __syncthreads();

    unsigned long long T = s_t[0];
#pragma unroll
    for (int w = 1; w < 4; ++w) { unsigned long long p = s_t[w]; T = (p > T) ? p : T; }

    // ---- Phase 3: collect candidates <= T ------------------------------
#pragma unroll
    for (int i = 0; i < PPT; ++i) {
        unsigned long long key =
            ((unsigned long long)ord[i] << 32) | (unsigned)(i * TB + t);
        if (key <= T) {
            int pos = atomicAdd(&s_cnt, 1);
            if (pos < CAP) s_cand[pos] = key;
        }
    }
    __syncthreads();
    const int cnt = s_cnt;

    if (cnt <= CAP) {
        // ---- Phase 4a: counting-sort ranks (keys unique) ---------------
        for (int j = t; j < cnt; j += TB) {
            const unsigned long long c = s_cand[j];
            int r = 0;
#pragma unroll 4
            for (int i = 0; i < cnt; ++i) r += (s_cand[i] < c) ? 1 : 0;
            if (r < GSZ) s_win[r] = (unsigned)c;   // low 32 bits = point index
        }
        __syncthreads();
    } else {
        // ---- Phase 4b: fallback — exact 32-round extraction ------------
        for (int k = 0; k < GSZ; ++k) {
            unsigned long long v = mymin;
#pragma unroll
            for (int m = 32; m >= 1; m >>= 1) {
                unsigned long long o = __shfl_xor(v, m, 64);
                v = (o < v) ? o : v;
            }
            if (lane == 0) s_t[t >> 6] = v;
            __syncthreads();
            unsigned long long gk = s_t[0];
#pragma unroll
            for (int w = 1; w < 4; ++w) {
                unsigned long long p = s_t[w];
                gk = (p < gk) ? p : gk;
            }
            if (t == 0) s_win[k] = (unsigned)gk;
            if (gk == mymin) {
                const int iwin = ((unsigned)gk) >> 8;   // n / 256
#pragma unroll
                for (int i = 0; i < PPT; ++i)
                    if (i == iwin) ord[i] = 0xFFFFFFFFu;
                mymin = ~0ull;
#pragma unroll
                for (int i = 0; i < PPT; ++i) {
                    unsigned long long kk =
                        ((unsigned long long)ord[i] << 32) | (unsigned)(i * TB + t);
                    mymin = (kk < mymin) ? kk : mymin;
                }
            }
            __syncthreads();
        }
    }

    // ---- Phase 5: outputs ---------------------------------------------
    if (t < GSZ) {
        const unsigned n = s_win[t] & 0x3FFFu;
        const float x0 = base[n * 3 + 0];
        const float x1 = base[n * 3 + 1];
        const float x2 = base[n * 3 + 2];
        const size_t ob = (((size_t)bg) * GSZ + t) * 3;
        out_nb[ob + 0] = x0 - c0;
        out_nb[ob + 1] = x1 - c1;
        out_nb[ob + 2] = x2 - c2;
    }
    if (t < 3) out_ctr[(size_t)bg * 3 + t] = base[nc * 3 + t];
    if (t == 0) out_ids[bg] = (float)nc;
}

extern "C" void kernel_launch(void* const* d_in, const int* in_sizes, int n_in,
                              void* d_out, int out_size, void* d_ws, size_t ws_size,
                              hipStream_t stream) {
    const float* xyz = (const float*)d_in[0];
    float* out = (float*)d_out;
    float* out_nb  = out;                        // 786432
    float* out_ctr = out + 786432;               // 24576
    float* out_ids = out + 786432 + 24576;       // 8192
    hipLaunchKernelGGL(group_knn_kernel, dim3(16 * 512), dim3(TB), 0, stream,
                       xyz, out_nb, out_ctr, out_ids);
}